// Round 14
// baseline (232.245 us; speedup 1.0000x reference)
//
#include <hip/hip_runtime.h>
#include <math.h>

// ---------------------------------------------------------------------------
// GAT 2-layer forward. N=100k nodes, E=1.6M edges + N self-loops.
// R3: bf16 features. R4: packed-dword gathers. R5: W2-GEMM split. R12: LDS-
// free GEMMs (W in VGPRs). R13: bucket binning + per-bucket counting sort.
// R14: 16-edge batch in agg1 (VGPR headroom: 24/128), 32-edge tier in agg2,
//      v_pk_fma_f32 via float2 elementwise-fma for the lo/hi channel pair,
//      k_bbase fused into k_scan3.
// ---------------------------------------------------------------------------

#define LOG2E 1.4426950408889634f
#define NB  256   // binning blocks (contiguous chunks)
#define NBK 512   // buckets = dst >> 8

#if __has_builtin(__builtin_amdgcn_exp2f)
#define EXP2F(x) __builtin_amdgcn_exp2f(x)
#else
#define EXP2F(x) exp2f(x)
#endif

typedef float v2f __attribute__((ext_vector_type(2)));

static __device__ __forceinline__ unsigned short f2bf(float f) {
    unsigned int u = __float_as_uint(f);
    unsigned int r = (u + 0x7fffu + ((u >> 16) & 1u)) >> 16;   // RNE
    return (unsigned short)r;
}
static __device__ __forceinline__ float bf_lo(unsigned int w) {
    return __uint_as_float(w << 16);
}
static __device__ __forceinline__ float bf_hi(unsigned int w) {
    return __uint_as_float(w & 0xffff0000u);
}
static __device__ __forceinline__ v2f unpk(unsigned int w) {
    v2f r; r.x = bf_lo(w); r.y = bf_hi(w); return r;
}
static __device__ __forceinline__ v2f pkfma(float w, unsigned int u, v2f acc) {
    v2f wv; wv.x = w; wv.y = w;
    return __builtin_elementwise_fma(wv, unpk(u), acc);
}
static __device__ __forceinline__ float leaky(float x) {
    return fmaxf(x, 0.2f * x);
}
static __device__ __forceinline__ float rdlane(float v, int l) {
    return __uint_as_float(__builtin_amdgcn_readlane(__float_as_uint(v), l));
}

// Per-block (chunk=2048) exclusive scan, block totals to bsum. (Used on mat.)
__global__ void k_scan1(const int* __restrict__ cnt, int* __restrict__ off,
                        int* __restrict__ bsum, int n) {
    __shared__ int lds[256];
    int t = threadIdx.x;
    int base = blockIdx.x * 2048 + t * 8;
    int v[8]; int s = 0;
#pragma unroll
    for (int j = 0; j < 8; ++j) { int idx = base + j; v[j] = (idx < n) ? cnt[idx] : 0; s += v[j]; }
    lds[t] = s; __syncthreads();
    int inc = s;
    for (int d = 1; d < 256; d <<= 1) {
        int y = (t >= d) ? lds[t - d] : 0;
        __syncthreads();
        inc += y; lds[t] = inc;
        __syncthreads();
    }
    int run = inc - s;
#pragma unroll
    for (int j = 0; j < 8; ++j) { int idx = base + j; if (idx < n) off[idx] = run; run += v[j]; }
    if (t == 255) bsum[blockIdx.x] = inc;
}

__global__ void k_scan2(int* __restrict__ bsum, int nb) {
    __shared__ int lds[1024];
    int t = threadIdx.x;
    int v = (t < nb) ? bsum[t] : 0;
    lds[t] = v; __syncthreads();
    int inc = v;
    for (int d = 1; d < 1024; d <<= 1) {
        int y = (t >= d) ? lds[t - d] : 0;
        __syncthreads();
        inc += y; lds[t] = inc;
        __syncthreads();
    }
    if (t < nb) bsum[t] = inc - v;   // exclusive block prefix
}

// Scan finalize + bucket bases + off terminator (k_bbase fused in).
__global__ void k_scan3(int* __restrict__ mat_s, const int* __restrict__ bsum,
                        int n, int total, int* __restrict__ bbase,
                        int* __restrict__ off, int nodes) {
    int i = blockIdx.x * blockDim.x + threadIdx.x;
    if (i < n) {
        int v = mat_s[i] + bsum[i / 2048];
        mat_s[i] = v;
        if ((i & (NB - 1)) == 0) bbase[i / NB] = v;
    }
    if (i == 0) { bbase[NBK] = total; off[nodes] = total; }
}

// Per-chunk bucket histogram -> mat[bucket][block] (bucket-major for the scan).
__global__ void k_binhist2(const int* __restrict__ ei, int E, int n,
                           int* __restrict__ mat) {
    __shared__ int lh[NBK];
    int t = threadIdx.x, b = blockIdx.x;
    for (int i = t; i < NBK; i += 256) lh[i] = 0;
    __syncthreads();
    int tot = E + n;
    int chunk = (tot + NB - 1) / NB;
    int b0 = b * chunk, b1 = min(b0 + chunk, tot);
    for (int i = b0 + t; i < b1; i += 256) {
        int d = (i < E) ? ei[E + i] : (i - E);
        atomicAdd(&lh[d >> 8], 1);
    }
    __syncthreads();
    for (int i = t; i < NBK; i += 256) mat[i * NB + b] = lh[i];
}

// Partition pairs into bucket segments using the scanned bases + LDS ranks.
__global__ void k_part2(const int* __restrict__ ei, int E, int n,
                        const int* __restrict__ mat_s, uint2* __restrict__ pairs) {
    __shared__ int lh[NBK];   // running rank within (block,bucket)
    __shared__ int lb[NBK];   // base for (block,bucket)
    int t = threadIdx.x, b = blockIdx.x;
    for (int i = t; i < NBK; i += 256) { lh[i] = 0; lb[i] = mat_s[i * NB + b]; }
    __syncthreads();
    int tot = E + n;
    int chunk = (tot + NB - 1) / NB;
    int b0 = b * chunk, b1 = min(b0 + chunk, tot);
    for (int i = b0 + t; i < b1; i += 256) {
        int s, d;
        if (i < E) { s = ei[i]; d = ei[E + i]; } else { s = d = i - E; }
        int bk = d >> 8;
        int r = atomicAdd(&lh[bk], 1);
        pairs[lb[bk] + r] = make_uint2((unsigned)s, (unsigned)d);
    }
}

// Per-bucket counting sort: block bk owns pairs [bbase[bk], bbase[bk+1]);
// LDS hist over the 256 local dsts -> LDS scan -> off[] directly; LDS-atomic
// ranks -> csr scatter into the block-private window.
__global__ void k_bsort(const uint2* __restrict__ pairs, const int* __restrict__ bbase,
                        int n, int* __restrict__ off, int* __restrict__ csr) {
    __shared__ int hist[256];
    __shared__ int lds[256];
    __shared__ int excl[256];
    __shared__ int curl[256];
    int t = threadIdx.x, bk = blockIdx.x;
    int p0 = bbase[bk], p1 = bbase[bk + 1];
    hist[t] = 0; curl[t] = 0;
    __syncthreads();
    for (int i = p0 + t; i < p1; i += 256)
        atomicAdd(&hist[pairs[i].y & 255u], 1);
    __syncthreads();
    int v = hist[t];
    lds[t] = v;
    __syncthreads();
    int inc = v;
    for (int d = 1; d < 256; d <<= 1) {
        int y = (t >= d) ? lds[t - d] : 0;
        __syncthreads();
        inc += y; lds[t] = inc;
        __syncthreads();
    }
    excl[t] = inc - v;
    int node = (bk << 8) + t;
    if (node < n) off[node] = p0 + excl[t];
    __syncthreads();
    for (int i = p0 + t; i < p1; i += 256) {
        uint2 pr = pairs[i];
        int l = (int)(pr.y & 255u);
        int r = atomicAdd(&curl[l], 1);
        csr[p0 + excl[l] + r] = (int)pr.x;
    }
}

// h1 = x @ W1  [N,64] stored bf16; logit halves as1/ad1 [N,2] fp32 * LOG2E.
// LDS-free: W1 column in 64 VGPRs; x broadcast via v_readlane.
__global__ void __launch_bounds__(256, 4)
k_gemm1(const float* __restrict__ x, const float* __restrict__ W1,
        const float* __restrict__ a_src1, const float* __restrict__ a_dst1,
        unsigned short* __restrict__ h1b, float* __restrict__ as1,
        float* __restrict__ ad1, int n) {
    int t = threadIdx.x;
    int lane = t & 63, wid = t >> 6;
    int head = lane >> 5, cc = lane & 31;
    float wreg[64];
#pragma unroll
    for (int k = 0; k < 64; ++k) wreg[k] = W1[k * 64 + lane];
    float asv = a_src1[head * 32 + cc], adv = a_dst1[head * 32 + cc];
    int nwaves = gridDim.x * 4;
    for (int node = blockIdx.x * 4 + wid; node < n; node += nwaves) {
        float xv = x[node * 64 + lane];
        float a0 = 0.f, a1 = 0.f, a2 = 0.f, a3 = 0.f;
#pragma unroll
        for (int k = 0; k < 64; k += 4) {
            a0 = fmaf(rdlane(xv, k + 0), wreg[k + 0], a0);
            a1 = fmaf(rdlane(xv, k + 1), wreg[k + 1], a1);
            a2 = fmaf(rdlane(xv, k + 2), wreg[k + 2], a2);
            a3 = fmaf(rdlane(xv, k + 3), wreg[k + 3], a3);
        }
        float acc = (a0 + a1) + (a2 + a3);
        h1b[node * 64 + lane] = f2bf(acc);
        float ps = acc * asv, pd = acc * adv;
        for (int d = 16; d > 0; d >>= 1) { ps += __shfl_xor(ps, d, 64); pd += __shfl_xor(pd, d, 64); }
        if (cc == 0) { as1[node * 2 + head] = ps * LOG2E; ad1[node * 2 + head] = pd * LOG2E; }
    }
}

// Layer-1 aggregation + bias + exact GELU -> packed bf16 g [N,32 words].
// One wave per node; half-wave per edge row; 16-edge batch (8/half-wave);
// pk_fma accumulation.
__global__ void __launch_bounds__(256, 4)
k_agg1(const unsigned int* __restrict__ h1w, const float* __restrict__ as1,
       const float* __restrict__ ad1, const float* __restrict__ b1,
       const int* __restrict__ off, const int* __restrict__ csr_src,
       unsigned int* __restrict__ gw, int n) {
    __shared__ float b1_lds[64];
    int t = threadIdx.x;
    if (t < 64) b1_lds[t] = b1[t];
    __syncthreads();
    int lane = t & 63, wid = t >> 6;
    int h = lane >> 5;          // which edge of the pair
    int c = lane & 31;          // packed word index (channels 2c, 2c+1)
    int head = c >> 4;          // both channels of a word share a head
    int nwaves = gridDim.x * 4;
    for (int node = blockIdx.x * 4 + wid; node < n; node += nwaves) {
        float adh = ad1[node * 2 + head];
        v2f acc = {0.f, 0.f};
        float wsum = 0.f;
        int p = off[node], pe = off[node + 1];
        for (; p + 16 <= pe; p += 16) {
            int s0 = csr_src[p + 0 + h];
            int s1 = csr_src[p + 2 + h];
            int s2 = csr_src[p + 4 + h];
            int s3 = csr_src[p + 6 + h];
            int s4 = csr_src[p + 8 + h];
            int s5 = csr_src[p + 10 + h];
            int s6 = csr_src[p + 12 + h];
            int s7 = csr_src[p + 14 + h];
            float a0 = as1[s0 * 2 + head], a1 = as1[s1 * 2 + head];
            float a2 = as1[s2 * 2 + head], a3 = as1[s3 * 2 + head];
            float a4 = as1[s4 * 2 + head], a5 = as1[s5 * 2 + head];
            float a6 = as1[s6 * 2 + head], a7 = as1[s7 * 2 + head];
            unsigned int u0 = h1w[s0 * 32 + c], u1 = h1w[s1 * 32 + c];
            unsigned int u2 = h1w[s2 * 32 + c], u3 = h1w[s3 * 32 + c];
            unsigned int u4 = h1w[s4 * 32 + c], u5 = h1w[s5 * 32 + c];
            unsigned int u6 = h1w[s6 * 32 + c], u7 = h1w[s7 * 32 + c];
            float w0 = EXP2F(leaky(a0 + adh));
            float w1 = EXP2F(leaky(a1 + adh));
            float w2 = EXP2F(leaky(a2 + adh));
            float w3 = EXP2F(leaky(a3 + adh));
            float w4 = EXP2F(leaky(a4 + adh));
            float w5 = EXP2F(leaky(a5 + adh));
            float w6 = EXP2F(leaky(a6 + adh));
            float w7 = EXP2F(leaky(a7 + adh));
            wsum += ((w0 + w1) + (w2 + w3)) + ((w4 + w5) + (w6 + w7));
            acc = pkfma(w0, u0, acc);
            acc = pkfma(w1, u1, acc);
            acc = pkfma(w2, u2, acc);
            acc = pkfma(w3, u3, acc);
            acc = pkfma(w4, u4, acc);
            acc = pkfma(w5, u5, acc);
            acc = pkfma(w6, u6, acc);
            acc = pkfma(w7, u7, acc);
        }
        for (; p + 8 <= pe; p += 8) {
            int s0 = csr_src[p + 0 + h];
            int s1 = csr_src[p + 2 + h];
            int s2 = csr_src[p + 4 + h];
            int s3 = csr_src[p + 6 + h];
            float a0 = as1[s0 * 2 + head], a1 = as1[s1 * 2 + head];
            float a2 = as1[s2 * 2 + head], a3 = as1[s3 * 2 + head];
            unsigned int u0 = h1w[s0 * 32 + c], u1 = h1w[s1 * 32 + c];
            unsigned int u2 = h1w[s2 * 32 + c], u3 = h1w[s3 * 32 + c];
            float w0 = EXP2F(leaky(a0 + adh));
            float w1 = EXP2F(leaky(a1 + adh));
            float w2 = EXP2F(leaky(a2 + adh));
            float w3 = EXP2F(leaky(a3 + adh));
            wsum += (w0 + w1) + (w2 + w3);
            acc = pkfma(w0, u0, acc);
            acc = pkfma(w1, u1, acc);
            acc = pkfma(w2, u2, acc);
            acc = pkfma(w3, u3, acc);
        }
        for (; p < pe; p += 2) {
            if (p + h < pe) {
                int s = csr_src[p + h];
                float w = EXP2F(leaky(as1[s * 2 + head] + adh));
                unsigned int u = h1w[s * 32 + c];
                wsum += w;
                acc = pkfma(w, u, acc);
            }
        }
        // combine the two half-wave edge streams
        float acc_lo = acc.x, acc_hi = acc.y;
        acc_lo += __shfl_xor(acc_lo, 32, 64);
        acc_hi += __shfl_xor(acc_hi, 32, 64);
        wsum   += __shfl_xor(wsum, 32, 64);
        float inv = 1.0f / wsum;
        float g_lo = acc_lo * inv + b1_lds[2 * c];
        float g_hi = acc_hi * inv + b1_lds[2 * c + 1];
        g_lo = 0.5f * g_lo * (1.0f + erff(g_lo * 0.70710678118654752f));
        g_hi = 0.5f * g_hi * (1.0f + erff(g_hi * 0.70710678118654752f));
        if (lane < 32)
            gw[node * 32 + c] = (unsigned int)f2bf(g_lo) | ((unsigned int)f2bf(g_hi) << 16);
    }
}

// h2 = g @ W2 [N,32] packed bf16, plus layer-2 logits as2/ad2 (* LOG2E).
// LDS-free: W2 half-column in 32 VGPRs; g-row via L1-broadcast uint4 loads.
__global__ void __launch_bounds__(256, 4)
k_gemm2(const unsigned int* __restrict__ gw, const float* __restrict__ W2,
        const float* __restrict__ a_src2, const float* __restrict__ a_dst2,
        unsigned int* __restrict__ h2w, float* __restrict__ as2,
        float* __restrict__ ad2, int n) {
    int t = threadIdx.x;
    int lane = t & 63, wid = t >> 6;
    int cc = lane & 31;         // output column
    int kh = lane >> 5;         // K half
    float w2reg[32];
#pragma unroll
    for (int k = 0; k < 32; ++k) w2reg[k] = W2[(kh * 32 + k) * 32 + cc];
    float av_s = a_src2[cc] * LOG2E;
    float av_d = a_dst2[cc] * LOG2E;
    int kh8 = kh * 8;
    int nwaves = gridDim.x * 4;
    for (int node = blockIdx.x * 4 + wid; node < n; node += nwaves) {
        const uint4* gp = reinterpret_cast<const uint4*>(&gw[node * 32 + kh8 * 2]);
        uint4 ga = gp[0];
        uint4 gb = gp[1];
        float acc2 = 0.f;
        acc2 = fmaf(bf_lo(ga.x), w2reg[0], acc2);  acc2 = fmaf(bf_hi(ga.x), w2reg[1], acc2);
        acc2 = fmaf(bf_lo(ga.y), w2reg[2], acc2);  acc2 = fmaf(bf_hi(ga.y), w2reg[3], acc2);
        acc2 = fmaf(bf_lo(ga.z), w2reg[4], acc2);  acc2 = fmaf(bf_hi(ga.z), w2reg[5], acc2);
        acc2 = fmaf(bf_lo(ga.w), w2reg[6], acc2);  acc2 = fmaf(bf_hi(ga.w), w2reg[7], acc2);
        acc2 = fmaf(bf_lo(gb.x), w2reg[8], acc2);  acc2 = fmaf(bf_hi(gb.x), w2reg[9], acc2);
        acc2 = fmaf(bf_lo(gb.y), w2reg[10], acc2); acc2 = fmaf(bf_hi(gb.y), w2reg[11], acc2);
        acc2 = fmaf(bf_lo(gb.z), w2reg[12], acc2); acc2 = fmaf(bf_hi(gb.z), w2reg[13], acc2);
        acc2 = fmaf(bf_lo(gb.w), w2reg[14], acc2); acc2 = fmaf(bf_hi(gb.w), w2reg[15], acc2);
        uint4 gc = gp[2];
        uint4 gd = gp[3];
        acc2 = fmaf(bf_lo(gc.x), w2reg[16], acc2); acc2 = fmaf(bf_hi(gc.x), w2reg[17], acc2);
        acc2 = fmaf(bf_lo(gc.y), w2reg[18], acc2); acc2 = fmaf(bf_hi(gc.y), w2reg[19], acc2);
        acc2 = fmaf(bf_lo(gc.z), w2reg[20], acc2); acc2 = fmaf(bf_hi(gc.z), w2reg[21], acc2);
        acc2 = fmaf(bf_lo(gc.w), w2reg[22], acc2); acc2 = fmaf(bf_hi(gc.w), w2reg[23], acc2);
        acc2 = fmaf(bf_lo(gd.x), w2reg[24], acc2); acc2 = fmaf(bf_hi(gd.x), w2reg[25], acc2);
        acc2 = fmaf(bf_lo(gd.y), w2reg[26], acc2); acc2 = fmaf(bf_hi(gd.y), w2reg[27], acc2);
        acc2 = fmaf(bf_lo(gd.z), w2reg[28], acc2); acc2 = fmaf(bf_hi(gd.z), w2reg[29], acc2);
        acc2 = fmaf(bf_lo(gd.w), w2reg[30], acc2); acc2 = fmaf(bf_hi(gd.w), w2reg[31], acc2);
        acc2 += __shfl_xor(acc2, 32, 64);       // full K sum, all lanes
        float ps = acc2 * av_s;
        float pd = acc2 * av_d;
        for (int d = 16; d > 0; d >>= 1) { ps += __shfl_xor(ps, d, 32); pd += __shfl_xor(pd, d, 32); }
        float nb = __shfl_xor(acc2, 1, 32);     // neighbor column value
        if (lane < 32 && !(cc & 1))
            h2w[node * 16 + (cc >> 1)] = (unsigned int)f2bf(acc2) | ((unsigned int)f2bf(nb) << 16);
        if (lane == 0) { as2[node] = ps; ad2[node] = pd; }
    }
}

// Layer-2 aggregation: one wave per node, quarter-wave per edge row;
// 32/16/8-edge batch tiers; pk_fma accumulation.
__global__ void __launch_bounds__(256, 4)
k_agg2(const unsigned int* __restrict__ h2w, const float* __restrict__ as2,
       const float* __restrict__ ad2, const float* __restrict__ b2,
       const int* __restrict__ off, const int* __restrict__ csr_src,
       float* __restrict__ out, int n) {
    int t = threadIdx.x;
    int lane = t & 63, wid = t >> 6;
    int q = lane >> 4;          // which edge of the quad
    int c = lane & 15;          // packed word index (channels 2c, 2c+1)
    int nwaves = gridDim.x * 4;
    for (int node = blockIdx.x * 4 + wid; node < n; node += nwaves) {
        float adv = ad2[node];
        v2f acc = {0.f, 0.f};
        float wsum = 0.f;
        int p = off[node], pe = off[node + 1];
        for (; p + 32 <= pe; p += 32) {
            int s0 = csr_src[p + 0 + q];
            int s1 = csr_src[p + 4 + q];
            int s2 = csr_src[p + 8 + q];
            int s3 = csr_src[p + 12 + q];
            int s4 = csr_src[p + 16 + q];
            int s5 = csr_src[p + 20 + q];
            int s6 = csr_src[p + 24 + q];
            int s7 = csr_src[p + 28 + q];
            float a0 = as2[s0], a1 = as2[s1], a2 = as2[s2], a3 = as2[s3];
            float a4 = as2[s4], a5 = as2[s5], a6 = as2[s6], a7 = as2[s7];
            unsigned int u0 = h2w[s0 * 16 + c], u1 = h2w[s1 * 16 + c];
            unsigned int u2 = h2w[s2 * 16 + c], u3 = h2w[s3 * 16 + c];
            unsigned int u4 = h2w[s4 * 16 + c], u5 = h2w[s5 * 16 + c];
            unsigned int u6 = h2w[s6 * 16 + c], u7 = h2w[s7 * 16 + c];
            float w0 = EXP2F(leaky(a0 + adv));
            float w1 = EXP2F(leaky(a1 + adv));
            float w2 = EXP2F(leaky(a2 + adv));
            float w3 = EXP2F(leaky(a3 + adv));
            float w4 = EXP2F(leaky(a4 + adv));
            float w5 = EXP2F(leaky(a5 + adv));
            float w6 = EXP2F(leaky(a6 + adv));
            float w7 = EXP2F(leaky(a7 + adv));
            wsum += ((w0 + w1) + (w2 + w3)) + ((w4 + w5) + (w6 + w7));
            acc = pkfma(w0, u0, acc);
            acc = pkfma(w1, u1, acc);
            acc = pkfma(w2, u2, acc);
            acc = pkfma(w3, u3, acc);
            acc = pkfma(w4, u4, acc);
            acc = pkfma(w5, u5, acc);
            acc = pkfma(w6, u6, acc);
            acc = pkfma(w7, u7, acc);
        }
        for (; p + 16 <= pe; p += 16) {
            int s0 = csr_src[p + 0 + q];
            int s1 = csr_src[p + 4 + q];
            int s2 = csr_src[p + 8 + q];
            int s3 = csr_src[p + 12 + q];
            float a0 = as2[s0], a1 = as2[s1], a2 = as2[s2], a3 = as2[s3];
            unsigned int u0 = h2w[s0 * 16 + c], u1 = h2w[s1 * 16 + c];
            unsigned int u2 = h2w[s2 * 16 + c], u3 = h2w[s3 * 16 + c];
            float w0 = EXP2F(leaky(a0 + adv));
            float w1 = EXP2F(leaky(a1 + adv));
            float w2 = EXP2F(leaky(a2 + adv));
            float w3 = EXP2F(leaky(a3 + adv));
            wsum += (w0 + w1) + (w2 + w3);
            acc = pkfma(w0, u0, acc);
            acc = pkfma(w1, u1, acc);
            acc = pkfma(w2, u2, acc);
            acc = pkfma(w3, u3, acc);
        }
        for (; p + 8 <= pe; p += 8) {
            int s0 = csr_src[p + 0 + q];
            int s1 = csr_src[p + 4 + q];
            float a0 = as2[s0], a1 = as2[s1];
            unsigned int u0 = h2w[s0 * 16 + c], u1 = h2w[s1 * 16 + c];
            float w0 = EXP2F(leaky(a0 + adv));
            float w1 = EXP2F(leaky(a1 + adv));
            wsum += w0 + w1;
            acc = pkfma(w0, u0, acc);
            acc = pkfma(w1, u1, acc);
        }
        for (; p < pe; p += 4) {
            if (p + q < pe) {
                int s = csr_src[p + q];
                float w = EXP2F(leaky(as2[s] + adv));
                unsigned int u = h2w[s * 16 + c];
                wsum += w;
                acc = pkfma(w, u, acc);
            }
        }
        // combine the four quarter-wave edge streams
        float acc_lo = acc.x, acc_hi = acc.y;
        acc_lo += __shfl_xor(acc_lo, 32, 64);
        acc_hi += __shfl_xor(acc_hi, 32, 64);
        wsum   += __shfl_xor(wsum, 32, 64);
        acc_lo += __shfl_xor(acc_lo, 16, 64);
        acc_hi += __shfl_xor(acc_hi, 16, 64);
        wsum   += __shfl_xor(wsum, 16, 64);
        if (lane < 16) {
            float inv = 1.0f / wsum;
            float2 o;
            o.x = acc_lo * inv + b2[2 * c];
            o.y = acc_hi * inv + b2[2 * c + 1];
            *reinterpret_cast<float2*>(&out[node * 32 + 2 * c]) = o;
        }
    }
}

extern "C" void kernel_launch(void* const* d_in, const int* in_sizes, int n_in,
                              void* d_out, int out_size, void* d_ws, size_t ws_size,
                              hipStream_t stream) {
    const float* x      = (const float*)d_in[0];
    const int*   ei     = (const int*)d_in[1];
    const float* W1     = (const float*)d_in[2];
    const float* a_src1 = (const float*)d_in[3];
    const float* a_dst1 = (const float*)d_in[4];
    const float* b1     = (const float*)d_in[5];
    const float* W2     = (const float*)d_in[6];
    const float* a_src2 = (const float*)d_in[7];
    const float* a_dst2 = (const float*)d_in[8];
    const float* b2     = (const float*)d_in[9];
    float* out = (float*)d_out;

    int n   = in_sizes[0] / 64;
    int E   = in_sizes[1] / 2;
    int tot = E + n;
    const int MATN = NBK * NB;   // 131072

    char* w = (char*)d_ws;
    int* off   = (int*)w; w += sizeof(int) * (size_t)(n + 1);
    int* bsum  = (int*)w; w += sizeof(int) * 1024;
    int* csr   = (int*)w; w += sizeof(int) * (size_t)tot;
    int* mat   = (int*)w; w += sizeof(int) * (size_t)MATN;
    int* mat_s = (int*)w; w += sizeof(int) * (size_t)(MATN + 1);
    int* bbase = (int*)w; w += sizeof(int) * (NBK + 1);
    unsigned short* h1b = (unsigned short*)w; w += sizeof(unsigned short) * (size_t)n * 64;
    float* as1 = (float*)w; w += sizeof(float) * (size_t)n * 2;
    float* ad1 = (float*)w; w += sizeof(float) * (size_t)n * 2;
    unsigned int* gw = (unsigned int*)w; w += sizeof(unsigned int) * (size_t)n * 32;
    float* as2v = (float*)w; w += sizeof(float) * (size_t)n;
    float* ad2v = (float*)w; w += sizeof(float) * (size_t)n;
    // pairs ([tot] uint2, 13.6MB) aliases h1b..as1 (written only after k_bsort).
    uint2* pairs = (uint2*)(((uintptr_t)h1b + 15) & ~(uintptr_t)15);
    // h2 (packed bf16, [n,16 words]) aliases h1b (dead after k_agg1).
    unsigned int* h2w = (unsigned int*)h1b;

    k_binhist2<<<NB, 256, 0, stream>>>(ei, E, n, mat);
    k_scan1<<<MATN / 2048, 256, 0, stream>>>(mat, mat_s, bsum, MATN);
    k_scan2<<<1, 1024, 0, stream>>>(bsum, MATN / 2048);
    k_scan3<<<(MATN + 255) / 256, 256, 0, stream>>>(mat_s, bsum, MATN, tot, bbase, off, n);
    k_part2<<<NB, 256, 0, stream>>>(ei, E, n, mat_s, pairs);
    k_bsort<<<NBK, 256, 0, stream>>>(pairs, bbase, n, off, csr);
    k_gemm1<<<1024, 256, 0, stream>>>(x, W1, a_src1, a_dst1, h1b, as1, ad1, n);
    k_agg1<<<2048, 256, 0, stream>>>((const unsigned int*)h1b, as1, ad1, b1,
                                     off, csr, gw, n);
    k_gemm2<<<1024, 256, 0, stream>>>(gw, W2, a_src2, a_dst2, h2w, as2v, ad2v, n);
    k_agg2<<<2048, 256, 0, stream>>>(h2w, as2v, ad2v, b2, off, csr, out, n);
}

// Round 15
// 229.281 us; speedup vs baseline: 1.0129x; 1.0129x over previous
//
#include <hip/hip_runtime.h>
#include <math.h>

// ---------------------------------------------------------------------------
// GAT 2-layer forward. N=100k nodes, E=1.6M edges + N self-loops.
// R3: bf16 features. R4: packed-dword gathers. R5: W2-GEMM split. R12: LDS-
// free GEMMs. R13: bucket binning + per-bucket counting sort.
// R14 REVERTED: 16-edge batch + pk_fma dropped occupancy 70->46% (VGPR 24->36)
//      and regressed agg1 66->86us. Back to R13's 8-edge scalar-fmaf loops.
// R15: edge-weight precompute k_wedge: wedge[p]={w_h0,w_h1}=exp2(leaky(
//      as1[csr[p]]+ad1[dstof[p]])). Removes the per-lane-redundant leaky+exp2
//      (~40% of agg1 loop VALU) and converts the random as1 gather into a
//      sequential lane-broadcast read. bsort also emits dstof[].
// ---------------------------------------------------------------------------

#define LOG2E 1.4426950408889634f
#define NB  256   // binning blocks (contiguous chunks)
#define NBK 512   // buckets = dst >> 8

#if __has_builtin(__builtin_amdgcn_exp2f)
#define EXP2F(x) __builtin_amdgcn_exp2f(x)
#else
#define EXP2F(x) exp2f(x)
#endif

static __device__ __forceinline__ unsigned short f2bf(float f) {
    unsigned int u = __float_as_uint(f);
    unsigned int r = (u + 0x7fffu + ((u >> 16) & 1u)) >> 16;   // RNE
    return (unsigned short)r;
}
static __device__ __forceinline__ float bf_lo(unsigned int w) {
    return __uint_as_float(w << 16);
}
static __device__ __forceinline__ float bf_hi(unsigned int w) {
    return __uint_as_float(w & 0xffff0000u);
}
static __device__ __forceinline__ float leaky(float x) {
    return fmaxf(x, 0.2f * x);
}
static __device__ __forceinline__ float rdlane(float v, int l) {
    return __uint_as_float(__builtin_amdgcn_readlane(__float_as_uint(v), l));
}

// Per-block (chunk=2048) exclusive scan, block totals to bsum. (Used on mat.)
__global__ void k_scan1(const int* __restrict__ cnt, int* __restrict__ off,
                        int* __restrict__ bsum, int n) {
    __shared__ int lds[256];
    int t = threadIdx.x;
    int base = blockIdx.x * 2048 + t * 8;
    int v[8]; int s = 0;
#pragma unroll
    for (int j = 0; j < 8; ++j) { int idx = base + j; v[j] = (idx < n) ? cnt[idx] : 0; s += v[j]; }
    lds[t] = s; __syncthreads();
    int inc = s;
    for (int d = 1; d < 256; d <<= 1) {
        int y = (t >= d) ? lds[t - d] : 0;
        __syncthreads();
        inc += y; lds[t] = inc;
        __syncthreads();
    }
    int run = inc - s;
#pragma unroll
    for (int j = 0; j < 8; ++j) { int idx = base + j; if (idx < n) off[idx] = run; run += v[j]; }
    if (t == 255) bsum[blockIdx.x] = inc;
}

__global__ void k_scan2(int* __restrict__ bsum, int nb) {
    __shared__ int lds[1024];
    int t = threadIdx.x;
    int v = (t < nb) ? bsum[t] : 0;
    lds[t] = v; __syncthreads();
    int inc = v;
    for (int d = 1; d < 1024; d <<= 1) {
        int y = (t >= d) ? lds[t - d] : 0;
        __syncthreads();
        inc += y; lds[t] = inc;
        __syncthreads();
    }
    if (t < nb) bsum[t] = inc - v;   // exclusive block prefix
}

// Scan finalize + bucket bases + off terminator (k_bbase fused in).
__global__ void k_scan3(int* __restrict__ mat_s, const int* __restrict__ bsum,
                        int n, int total, int* __restrict__ bbase,
                        int* __restrict__ off, int nodes) {
    int i = blockIdx.x * blockDim.x + threadIdx.x;
    if (i < n) {
        int v = mat_s[i] + bsum[i / 2048];
        mat_s[i] = v;
        if ((i & (NB - 1)) == 0) bbase[i / NB] = v;
    }
    if (i == 0) { bbase[NBK] = total; off[nodes] = total; }
}

// Per-chunk bucket histogram -> mat[bucket][block] (bucket-major for the scan).
__global__ void k_binhist2(const int* __restrict__ ei, int E, int n,
                           int* __restrict__ mat) {
    __shared__ int lh[NBK];
    int t = threadIdx.x, b = blockIdx.x;
    for (int i = t; i < NBK; i += 256) lh[i] = 0;
    __syncthreads();
    int tot = E + n;
    int chunk = (tot + NB - 1) / NB;
    int b0 = b * chunk, b1 = min(b0 + chunk, tot);
    for (int i = b0 + t; i < b1; i += 256) {
        int d = (i < E) ? ei[E + i] : (i - E);
        atomicAdd(&lh[d >> 8], 1);
    }
    __syncthreads();
    for (int i = t; i < NBK; i += 256) mat[i * NB + b] = lh[i];
}

// Partition pairs into bucket segments using the scanned bases + LDS ranks.
__global__ void k_part2(const int* __restrict__ ei, int E, int n,
                        const int* __restrict__ mat_s, uint2* __restrict__ pairs) {
    __shared__ int lh[NBK];   // running rank within (block,bucket)
    __shared__ int lb[NBK];   // base for (block,bucket)
    int t = threadIdx.x, b = blockIdx.x;
    for (int i = t; i < NBK; i += 256) { lh[i] = 0; lb[i] = mat_s[i * NB + b]; }
    __syncthreads();
    int tot = E + n;
    int chunk = (tot + NB - 1) / NB;
    int b0 = b * chunk, b1 = min(b0 + chunk, tot);
    for (int i = b0 + t; i < b1; i += 256) {
        int s, d;
        if (i < E) { s = ei[i]; d = ei[E + i]; } else { s = d = i - E; }
        int bk = d >> 8;
        int r = atomicAdd(&lh[bk], 1);
        pairs[lb[bk] + r] = make_uint2((unsigned)s, (unsigned)d);
    }
}

// Per-bucket counting sort: block bk owns pairs [bbase[bk], bbase[bk+1]);
// LDS hist -> LDS scan -> off[]; LDS-atomic ranks -> csr + dstof scatter
// into the block-private window.
__global__ void k_bsort(const uint2* __restrict__ pairs, const int* __restrict__ bbase,
                        int n, int* __restrict__ off, int* __restrict__ csr,
                        int* __restrict__ dstof) {
    __shared__ int hist[256];
    __shared__ int lds[256];
    __shared__ int excl[256];
    __shared__ int curl[256];
    int t = threadIdx.x, bk = blockIdx.x;
    int p0 = bbase[bk], p1 = bbase[bk + 1];
    hist[t] = 0; curl[t] = 0;
    __syncthreads();
    for (int i = p0 + t; i < p1; i += 256)
        atomicAdd(&hist[pairs[i].y & 255u], 1);
    __syncthreads();
    int v = hist[t];
    lds[t] = v;
    __syncthreads();
    int inc = v;
    for (int d = 1; d < 256; d <<= 1) {
        int y = (t >= d) ? lds[t - d] : 0;
        __syncthreads();
        inc += y; lds[t] = inc;
        __syncthreads();
    }
    excl[t] = inc - v;
    int node = (bk << 8) + t;
    if (node < n) off[node] = p0 + excl[t];
    __syncthreads();
    for (int i = p0 + t; i < p1; i += 256) {
        uint2 pr = pairs[i];
        int l = (int)(pr.y & 255u);
        int r = atomicAdd(&curl[l], 1);
        int pos = p0 + excl[l] + r;
        csr[pos] = (int)pr.x;
        dstof[pos] = (int)pr.y;
    }
}

// Edge weights for layer 1: wedge[p] = exp2(leaky(as1[src] + ad1[dst])), both
// heads. csr/dstof sequential; as1/ad1 gathers are L2-resident (800KB each).
__global__ void k_wedge(const int* __restrict__ csr, const int* __restrict__ dstof,
                        const float2* __restrict__ as1v, const float2* __restrict__ ad1v,
                        float2* __restrict__ wedge, int tot) {
    int i = blockIdx.x * blockDim.x + threadIdx.x;
    if (i >= tot) return;
    float2 a = as1v[csr[i]];
    float2 d = ad1v[dstof[i]];
    float2 w;
    w.x = EXP2F(leaky(a.x + d.x));
    w.y = EXP2F(leaky(a.y + d.y));
    wedge[i] = w;
}

// h1 = x @ W1  [N,64] stored bf16; logit halves as1/ad1 [N,2] fp32 * LOG2E.
// LDS-free: W1 column in 64 VGPRs; x broadcast via v_readlane.
__global__ void __launch_bounds__(256, 4)
k_gemm1(const float* __restrict__ x, const float* __restrict__ W1,
        const float* __restrict__ a_src1, const float* __restrict__ a_dst1,
        unsigned short* __restrict__ h1b, float* __restrict__ as1,
        float* __restrict__ ad1, int n) {
    int t = threadIdx.x;
    int lane = t & 63, wid = t >> 6;
    int head = lane >> 5, cc = lane & 31;
    float wreg[64];
#pragma unroll
    for (int k = 0; k < 64; ++k) wreg[k] = W1[k * 64 + lane];
    float asv = a_src1[head * 32 + cc], adv = a_dst1[head * 32 + cc];
    int nwaves = gridDim.x * 4;
    for (int node = blockIdx.x * 4 + wid; node < n; node += nwaves) {
        float xv = x[node * 64 + lane];
        float a0 = 0.f, a1 = 0.f, a2 = 0.f, a3 = 0.f;
#pragma unroll
        for (int k = 0; k < 64; k += 4) {
            a0 = fmaf(rdlane(xv, k + 0), wreg[k + 0], a0);
            a1 = fmaf(rdlane(xv, k + 1), wreg[k + 1], a1);
            a2 = fmaf(rdlane(xv, k + 2), wreg[k + 2], a2);
            a3 = fmaf(rdlane(xv, k + 3), wreg[k + 3], a3);
        }
        float acc = (a0 + a1) + (a2 + a3);
        h1b[node * 64 + lane] = f2bf(acc);
        float ps = acc * asv, pd = acc * adv;
        for (int d = 16; d > 0; d >>= 1) { ps += __shfl_xor(ps, d, 64); pd += __shfl_xor(pd, d, 64); }
        if (cc == 0) { as1[node * 2 + head] = ps * LOG2E; ad1[node * 2 + head] = pd * LOG2E; }
    }
}

// Layer-1 aggregation + bias + exact GELU -> packed bf16 g [N,32 words].
// One wave per node; half-wave per edge row; 8-edge batch (R13 structure);
// weights from wedge[] (precomputed, lane-broadcast sequential reads).
__global__ void __launch_bounds__(256, 4)
k_agg1(const unsigned int* __restrict__ h1w, const float2* __restrict__ wedge,
       const float* __restrict__ b1,
       const int* __restrict__ off, const int* __restrict__ csr_src,
       unsigned int* __restrict__ gw, int n) {
    __shared__ float b1_lds[64];
    int t = threadIdx.x;
    if (t < 64) b1_lds[t] = b1[t];
    __syncthreads();
    int lane = t & 63, wid = t >> 6;
    int h = lane >> 5;          // which edge of the pair
    int c = lane & 31;          // packed word index (channels 2c, 2c+1)
    int head = c >> 4;          // both channels of a word share a head
    int nwaves = gridDim.x * 4;
    for (int node = blockIdx.x * 4 + wid; node < n; node += nwaves) {
        float acc_lo = 0.f, acc_hi = 0.f, wsum = 0.f;
        int p = off[node], pe = off[node + 1];
        for (; p + 8 <= pe; p += 8) {
            int i0 = p + 0 + h, i1 = p + 2 + h, i2 = p + 4 + h, i3 = p + 6 + h;
            int s0 = csr_src[i0];
            int s1 = csr_src[i1];
            int s2 = csr_src[i2];
            int s3 = csr_src[i3];
            float2 e0 = wedge[i0];
            float2 e1 = wedge[i1];
            float2 e2 = wedge[i2];
            float2 e3 = wedge[i3];
            unsigned int u0 = h1w[s0 * 32 + c];
            unsigned int u1 = h1w[s1 * 32 + c];
            unsigned int u2 = h1w[s2 * 32 + c];
            unsigned int u3 = h1w[s3 * 32 + c];
            float w0 = head ? e0.y : e0.x;
            float w1 = head ? e1.y : e1.x;
            float w2 = head ? e2.y : e2.x;
            float w3 = head ? e3.y : e3.x;
            wsum += (w0 + w1) + (w2 + w3);
            acc_lo = fmaf(w0, bf_lo(u0), acc_lo); acc_hi = fmaf(w0, bf_hi(u0), acc_hi);
            acc_lo = fmaf(w1, bf_lo(u1), acc_lo); acc_hi = fmaf(w1, bf_hi(u1), acc_hi);
            acc_lo = fmaf(w2, bf_lo(u2), acc_lo); acc_hi = fmaf(w2, bf_hi(u2), acc_hi);
            acc_lo = fmaf(w3, bf_lo(u3), acc_lo); acc_hi = fmaf(w3, bf_hi(u3), acc_hi);
        }
        for (; p < pe; p += 2) {
            if (p + h < pe) {
                int i = p + h;
                int s = csr_src[i];
                float2 e = wedge[i];
                float w = head ? e.y : e.x;
                unsigned int u = h1w[s * 32 + c];
                wsum += w;
                acc_lo = fmaf(w, bf_lo(u), acc_lo);
                acc_hi = fmaf(w, bf_hi(u), acc_hi);
            }
        }
        // combine the two half-wave edge streams
        acc_lo += __shfl_xor(acc_lo, 32, 64);
        acc_hi += __shfl_xor(acc_hi, 32, 64);
        wsum   += __shfl_xor(wsum, 32, 64);
        float inv = 1.0f / wsum;
        float g_lo = acc_lo * inv + b1_lds[2 * c];
        float g_hi = acc_hi * inv + b1_lds[2 * c + 1];
        g_lo = 0.5f * g_lo * (1.0f + erff(g_lo * 0.70710678118654752f));
        g_hi = 0.5f * g_hi * (1.0f + erff(g_hi * 0.70710678118654752f));
        if (lane < 32)
            gw[node * 32 + c] = (unsigned int)f2bf(g_lo) | ((unsigned int)f2bf(g_hi) << 16);
    }
}

// h2 = g @ W2 [N,32] packed bf16, plus layer-2 logits as2/ad2 (* LOG2E).
// LDS-free: W2 half-column in 32 VGPRs; g-row via L1-broadcast uint4 loads.
__global__ void __launch_bounds__(256, 4)
k_gemm2(const unsigned int* __restrict__ gw, const float* __restrict__ W2,
        const float* __restrict__ a_src2, const float* __restrict__ a_dst2,
        unsigned int* __restrict__ h2w, float* __restrict__ as2,
        float* __restrict__ ad2, int n) {
    int t = threadIdx.x;
    int lane = t & 63, wid = t >> 6;
    int cc = lane & 31;         // output column
    int kh = lane >> 5;         // K half
    float w2reg[32];
#pragma unroll
    for (int k = 0; k < 32; ++k) w2reg[k] = W2[(kh * 32 + k) * 32 + cc];
    float av_s = a_src2[cc] * LOG2E;
    float av_d = a_dst2[cc] * LOG2E;
    int kh8 = kh * 8;
    int nwaves = gridDim.x * 4;
    for (int node = blockIdx.x * 4 + wid; node < n; node += nwaves) {
        const uint4* gp = reinterpret_cast<const uint4*>(&gw[node * 32 + kh8 * 2]);
        uint4 ga = gp[0];
        uint4 gb = gp[1];
        float acc2 = 0.f;
        acc2 = fmaf(bf_lo(ga.x), w2reg[0], acc2);  acc2 = fmaf(bf_hi(ga.x), w2reg[1], acc2);
        acc2 = fmaf(bf_lo(ga.y), w2reg[2], acc2);  acc2 = fmaf(bf_hi(ga.y), w2reg[3], acc2);
        acc2 = fmaf(bf_lo(ga.z), w2reg[4], acc2);  acc2 = fmaf(bf_hi(ga.z), w2reg[5], acc2);
        acc2 = fmaf(bf_lo(ga.w), w2reg[6], acc2);  acc2 = fmaf(bf_hi(ga.w), w2reg[7], acc2);
        acc2 = fmaf(bf_lo(gb.x), w2reg[8], acc2);  acc2 = fmaf(bf_hi(gb.x), w2reg[9], acc2);
        acc2 = fmaf(bf_lo(gb.y), w2reg[10], acc2); acc2 = fmaf(bf_hi(gb.y), w2reg[11], acc2);
        acc2 = fmaf(bf_lo(gb.z), w2reg[12], acc2); acc2 = fmaf(bf_hi(gb.z), w2reg[13], acc2);
        acc2 = fmaf(bf_lo(gb.w), w2reg[14], acc2); acc2 = fmaf(bf_hi(gb.w), w2reg[15], acc2);
        uint4 gc = gp[2];
        uint4 gd = gp[3];
        acc2 = fmaf(bf_lo(gc.x), w2reg[16], acc2); acc2 = fmaf(bf_hi(gc.x), w2reg[17], acc2);
        acc2 = fmaf(bf_lo(gc.y), w2reg[18], acc2); acc2 = fmaf(bf_hi(gc.y), w2reg[19], acc2);
        acc2 = fmaf(bf_lo(gc.z), w2reg[20], acc2); acc2 = fmaf(bf_hi(gc.z), w2reg[21], acc2);
        acc2 = fmaf(bf_lo(gc.w), w2reg[22], acc2); acc2 = fmaf(bf_hi(gc.w), w2reg[23], acc2);
        acc2 = fmaf(bf_lo(gd.x), w2reg[24], acc2); acc2 = fmaf(bf_hi(gd.x), w2reg[25], acc2);
        acc2 = fmaf(bf_lo(gd.y), w2reg[26], acc2); acc2 = fmaf(bf_hi(gd.y), w2reg[27], acc2);
        acc2 = fmaf(bf_lo(gd.z), w2reg[28], acc2); acc2 = fmaf(bf_hi(gd.z), w2reg[29], acc2);
        acc2 = fmaf(bf_lo(gd.w), w2reg[30], acc2); acc2 = fmaf(bf_hi(gd.w), w2reg[31], acc2);
        acc2 += __shfl_xor(acc2, 32, 64);       // full K sum, all lanes
        float ps = acc2 * av_s;
        float pd = acc2 * av_d;
        for (int d = 16; d > 0; d >>= 1) { ps += __shfl_xor(ps, d, 32); pd += __shfl_xor(pd, d, 32); }
        float nb = __shfl_xor(acc2, 1, 32);     // neighbor column value
        if (lane < 32 && !(cc & 1))
            h2w[node * 16 + (cc >> 1)] = (unsigned int)f2bf(acc2) | ((unsigned int)f2bf(nb) << 16);
        if (lane == 0) { as2[node] = ps; ad2[node] = pd; }
    }
}

// Layer-2 aggregation: one wave per node, quarter-wave per edge row
// (lane owns 2 of 32 channels); 16-edge and 8-edge batch tiers. (R13 form.)
__global__ void __launch_bounds__(256, 4)
k_agg2(const unsigned int* __restrict__ h2w, const float* __restrict__ as2,
       const float* __restrict__ ad2, const float* __restrict__ b2,
       const int* __restrict__ off, const int* __restrict__ csr_src,
       float* __restrict__ out, int n) {
    int t = threadIdx.x;
    int lane = t & 63, wid = t >> 6;
    int q = lane >> 4;          // which edge of the quad
    int c = lane & 15;          // packed word index (channels 2c, 2c+1)
    int nwaves = gridDim.x * 4;
    for (int node = blockIdx.x * 4 + wid; node < n; node += nwaves) {
        float adv = ad2[node];
        float acc_lo = 0.f, acc_hi = 0.f, wsum = 0.f;
        int p = off[node], pe = off[node + 1];
        for (; p + 16 <= pe; p += 16) {
            int s0 = csr_src[p + 0 + q];
            int s1 = csr_src[p + 4 + q];
            int s2 = csr_src[p + 8 + q];
            int s3 = csr_src[p + 12 + q];
            float a0 = as2[s0], a1 = as2[s1], a2 = as2[s2], a3 = as2[s3];
            unsigned int u0 = h2w[s0 * 16 + c];
            unsigned int u1 = h2w[s1 * 16 + c];
            unsigned int u2 = h2w[s2 * 16 + c];
            unsigned int u3 = h2w[s3 * 16 + c];
            float w0 = EXP2F(leaky(a0 + adv));
            float w1 = EXP2F(leaky(a1 + adv));
            float w2 = EXP2F(leaky(a2 + adv));
            float w3 = EXP2F(leaky(a3 + adv));
            wsum += (w0 + w1) + (w2 + w3);
            acc_lo = fmaf(w0, bf_lo(u0), acc_lo); acc_hi = fmaf(w0, bf_hi(u0), acc_hi);
            acc_lo = fmaf(w1, bf_lo(u1), acc_lo); acc_hi = fmaf(w1, bf_hi(u1), acc_hi);
            acc_lo = fmaf(w2, bf_lo(u2), acc_lo); acc_hi = fmaf(w2, bf_hi(u2), acc_hi);
            acc_lo = fmaf(w3, bf_lo(u3), acc_lo); acc_hi = fmaf(w3, bf_hi(u3), acc_hi);
        }
        for (; p + 8 <= pe; p += 8) {
            int s0 = csr_src[p + 0 + q];
            int s1 = csr_src[p + 4 + q];
            float a0 = as2[s0], a1 = as2[s1];
            unsigned int u0 = h2w[s0 * 16 + c];
            unsigned int u1 = h2w[s1 * 16 + c];
            float w0 = EXP2F(leaky(a0 + adv));
            float w1 = EXP2F(leaky(a1 + adv));
            wsum += w0 + w1;
            acc_lo = fmaf(w0, bf_lo(u0), acc_lo); acc_hi = fmaf(w0, bf_hi(u0), acc_hi);
            acc_lo = fmaf(w1, bf_lo(u1), acc_lo); acc_hi = fmaf(w1, bf_hi(u1), acc_hi);
        }
        for (; p < pe; p += 4) {
            if (p + q < pe) {
                int s = csr_src[p + q];
                float w = EXP2F(leaky(as2[s] + adv));
                unsigned int u = h2w[s * 16 + c];
                wsum += w;
                acc_lo = fmaf(w, bf_lo(u), acc_lo);
                acc_hi = fmaf(w, bf_hi(u), acc_hi);
            }
        }
        // combine the four quarter-wave edge streams
        acc_lo += __shfl_xor(acc_lo, 32, 64);
        acc_hi += __shfl_xor(acc_hi, 32, 64);
        wsum   += __shfl_xor(wsum, 32, 64);
        acc_lo += __shfl_xor(acc_lo, 16, 64);
        acc_hi += __shfl_xor(acc_hi, 16, 64);
        wsum   += __shfl_xor(wsum, 16, 64);
        if (lane < 16) {
            float inv = 1.0f / wsum;
            float2 o;
            o.x = acc_lo * inv + b2[2 * c];
            o.y = acc_hi * inv + b2[2 * c + 1];
            *reinterpret_cast<float2*>(&out[node * 32 + 2 * c]) = o;
        }
    }
}

extern "C" void kernel_launch(void* const* d_in, const int* in_sizes, int n_in,
                              void* d_out, int out_size, void* d_ws, size_t ws_size,
                              hipStream_t stream) {
    const float* x      = (const float*)d_in[0];
    const int*   ei     = (const int*)d_in[1];
    const float* W1     = (const float*)d_in[2];
    const float* a_src1 = (const float*)d_in[3];
    const float* a_dst1 = (const float*)d_in[4];
    const float* b1     = (const float*)d_in[5];
    const float* W2     = (const float*)d_in[6];
    const float* a_src2 = (const float*)d_in[7];
    const float* a_dst2 = (const float*)d_in[8];
    const float* b2     = (const float*)d_in[9];
    float* out = (float*)d_out;

    int n   = in_sizes[0] / 64;
    int E   = in_sizes[1] / 2;
    int tot = E + n;
    const int MATN = NBK * NB;   // 131072

    char* w = (char*)d_ws;
    int* off   = (int*)w; w += sizeof(int) * (size_t)(n + 1);
    int* bsum  = (int*)w; w += sizeof(int) * 1024;
    int* csr   = (int*)w; w += sizeof(int) * (size_t)tot;
    int* dstof = (int*)w; w += sizeof(int) * (size_t)tot;
    int* mat   = (int*)w; w += sizeof(int) * (size_t)MATN;
    int* mat_s = (int*)w; w += sizeof(int) * (size_t)(MATN + 1);
    int* bbase = (int*)w; w += sizeof(int) * (NBK + 1);
    float2* wedge = (float2*)(((uintptr_t)w + 15) & ~(uintptr_t)15);
    w = (char*)wedge + sizeof(float2) * (size_t)tot;
    unsigned short* h1b = (unsigned short*)w; w += sizeof(unsigned short) * (size_t)n * 64;
    float* as1 = (float*)w; w += sizeof(float) * (size_t)n * 2;
    float* ad1 = (float*)w; w += sizeof(float) * (size_t)n * 2;
    unsigned int* gw = (unsigned int*)w; w += sizeof(unsigned int) * (size_t)n * 32;
    float* as2v = (float*)w; w += sizeof(float) * (size_t)n;
    float* ad2v = (float*)w; w += sizeof(float) * (size_t)n;
    // pairs ([tot] uint2, 13.6MB) aliases h1b..as1 (written only after k_bsort).
    uint2* pairs = (uint2*)(((uintptr_t)h1b + 15) & ~(uintptr_t)15);
    // h2 (packed bf16, [n,16 words]) aliases h1b (dead after k_agg1).
    unsigned int* h2w = (unsigned int*)h1b;

    k_binhist2<<<NB, 256, 0, stream>>>(ei, E, n, mat);
    k_scan1<<<MATN / 2048, 256, 0, stream>>>(mat, mat_s, bsum, MATN);
    k_scan2<<<1, 1024, 0, stream>>>(bsum, MATN / 2048);
    k_scan3<<<(MATN + 255) / 256, 256, 0, stream>>>(mat_s, bsum, MATN, tot, bbase, off, n);
    k_part2<<<NB, 256, 0, stream>>>(ei, E, n, mat_s, pairs);
    k_bsort<<<NBK, 256, 0, stream>>>(pairs, bbase, n, off, csr, dstof);
    k_gemm1<<<1024, 256, 0, stream>>>(x, W1, a_src1, a_dst1, h1b, as1, ad1, n);
    k_wedge<<<(tot + 255) / 256, 256, 0, stream>>>(csr, dstof, (const float2*)as1,
                                                   (const float2*)ad1, wedge, tot);
    k_agg1<<<2048, 256, 0, stream>>>((const unsigned int*)h1b, wedge, b1,
                                     off, csr, gw, n);
    k_gemm2<<<1024, 256, 0, stream>>>(gw, W2, a_src2, a_dst2, h2w, as2v, ad2v, n);
    k_agg2<<<2048, 256, 0, stream>>>(h2w, as2v, ad2v, b2, off, csr, out, n);
}

// Round 16
// 210.884 us; speedup vs baseline: 1.1013x; 1.0872x over previous
//
#include <hip/hip_runtime.h>
#include <math.h>

// ---------------------------------------------------------------------------
// GAT 2-layer forward. N=100k nodes, E=1.6M edges + N self-loops.
// R3: bf16 features. R4: packed-dword gathers. R5: W2-GEMM split. R12: LDS-
// free GEMMs. R13: bucket binning + per-bucket counting sort.
// R14/R15 REVERTED: 16-edge+pk_fma batch cost occupancy (66->86us); wedge
//      precompute saved VALU but agg1 is gather-throughput-bound (66->63us)
//      while costing ~13us in extra kernel+writes. Back to R13 agg loops.
// R16: launch fusion only -- scan2 (64-entry bsum prefix, recomputed
//      redundantly per block in LDS) and bbase are folded into scan3.
//      11 -> 9 dispatches.
// ---------------------------------------------------------------------------

#define LOG2E 1.4426950408889634f
#define NB  256   // binning blocks (contiguous chunks)
#define NBK 512   // buckets = dst >> 8

#if __has_builtin(__builtin_amdgcn_exp2f)
#define EXP2F(x) __builtin_amdgcn_exp2f(x)
#else
#define EXP2F(x) exp2f(x)
#endif

static __device__ __forceinline__ unsigned short f2bf(float f) {
    unsigned int u = __float_as_uint(f);
    unsigned int r = (u + 0x7fffu + ((u >> 16) & 1u)) >> 16;   // RNE
    return (unsigned short)r;
}
static __device__ __forceinline__ float bf_lo(unsigned int w) {
    return __uint_as_float(w << 16);
}
static __device__ __forceinline__ float bf_hi(unsigned int w) {
    return __uint_as_float(w & 0xffff0000u);
}
static __device__ __forceinline__ float leaky(float x) {
    return fmaxf(x, 0.2f * x);
}
static __device__ __forceinline__ float rdlane(float v, int l) {
    return __uint_as_float(__builtin_amdgcn_readlane(__float_as_uint(v), l));
}

// Per-block (chunk=2048) exclusive scan of mat, block totals to bsum.
__global__ void k_scan1(const int* __restrict__ cnt, int* __restrict__ off,
                        int* __restrict__ bsum, int n) {
    __shared__ int lds[256];
    int t = threadIdx.x;
    int base = blockIdx.x * 2048 + t * 8;
    int v[8]; int s = 0;
#pragma unroll
    for (int j = 0; j < 8; ++j) { int idx = base + j; v[j] = (idx < n) ? cnt[idx] : 0; s += v[j]; }
    lds[t] = s; __syncthreads();
    int inc = s;
    for (int d = 1; d < 256; d <<= 1) {
        int y = (t >= d) ? lds[t - d] : 0;
        __syncthreads();
        inc += y; lds[t] = inc;
        __syncthreads();
    }
    int run = inc - s;
#pragma unroll
    for (int j = 0; j < 8; ++j) { int idx = base + j; if (idx < n) off[idx] = run; run += v[j]; }
    if (t == 255) bsum[blockIdx.x] = inc;
}

// Scan finalize: each block redundantly computes the 64-entry bsum exclusive
// prefix in LDS (scan2 fused), applies it, and emits bucket bases (bbase
// fused) + the off[] terminator.
__global__ void k_scan3(int* __restrict__ mat_s, const int* __restrict__ bsum,
                        int n, int total, int* __restrict__ bbase,
                        int* __restrict__ off, int nodes) {
    __shared__ int lds[64];
    __shared__ int pref[64];
    int t = threadIdx.x;
    int v = 0;
    if (t < 64) { v = bsum[t]; lds[t] = v; }
    __syncthreads();
    for (int d = 1; d < 64; d <<= 1) {
        int y = 0;
        if (t < 64 && t >= d) y = lds[t - d];
        __syncthreads();
        if (t < 64) lds[t] += y;
        __syncthreads();
    }
    if (t < 64) pref[t] = lds[t] - v;   // exclusive prefix of chunk t
    __syncthreads();
    int i = blockIdx.x * blockDim.x + t;
    if (i < n) {
        int val = mat_s[i] + pref[i >> 11];
        mat_s[i] = val;
        if ((i & (NB - 1)) == 0) bbase[i / NB] = val;
    }
    if (i == 0) { bbase[NBK] = total; off[nodes] = total; }
}

// Per-chunk bucket histogram -> mat[bucket][block] (bucket-major for the scan).
__global__ void k_binhist2(const int* __restrict__ ei, int E, int n,
                           int* __restrict__ mat) {
    __shared__ int lh[NBK];
    int t = threadIdx.x, b = blockIdx.x;
    for (int i = t; i < NBK; i += 256) lh[i] = 0;
    __syncthreads();
    int tot = E + n;
    int chunk = (tot + NB - 1) / NB;
    int b0 = b * chunk, b1 = min(b0 + chunk, tot);
    for (int i = b0 + t; i < b1; i += 256) {
        int d = (i < E) ? ei[E + i] : (i - E);
        atomicAdd(&lh[d >> 8], 1);
    }
    __syncthreads();
    for (int i = t; i < NBK; i += 256) mat[i * NB + b] = lh[i];
}

// Partition pairs into bucket segments using the scanned bases + LDS ranks.
__global__ void k_part2(const int* __restrict__ ei, int E, int n,
                        const int* __restrict__ mat_s, uint2* __restrict__ pairs) {
    __shared__ int lh[NBK];   // running rank within (block,bucket)
    __shared__ int lb[NBK];   // base for (block,bucket)
    int t = threadIdx.x, b = blockIdx.x;
    for (int i = t; i < NBK; i += 256) { lh[i] = 0; lb[i] = mat_s[i * NB + b]; }
    __syncthreads();
    int tot = E + n;
    int chunk = (tot + NB - 1) / NB;
    int b0 = b * chunk, b1 = min(b0 + chunk, tot);
    for (int i = b0 + t; i < b1; i += 256) {
        int s, d;
        if (i < E) { s = ei[i]; d = ei[E + i]; } else { s = d = i - E; }
        int bk = d >> 8;
        int r = atomicAdd(&lh[bk], 1);
        pairs[lb[bk] + r] = make_uint2((unsigned)s, (unsigned)d);
    }
}

// Per-bucket counting sort: block bk owns pairs [bbase[bk], bbase[bk+1]);
// LDS hist -> LDS scan -> off[] directly; LDS-atomic ranks -> csr scatter
// into the block-private window.
__global__ void k_bsort(const uint2* __restrict__ pairs, const int* __restrict__ bbase,
                        int n, int* __restrict__ off, int* __restrict__ csr) {
    __shared__ int hist[256];
    __shared__ int lds[256];
    __shared__ int excl[256];
    __shared__ int curl[256];
    int t = threadIdx.x, bk = blockIdx.x;
    int p0 = bbase[bk], p1 = bbase[bk + 1];
    hist[t] = 0; curl[t] = 0;
    __syncthreads();
    for (int i = p0 + t; i < p1; i += 256)
        atomicAdd(&hist[pairs[i].y & 255u], 1);
    __syncthreads();
    int v = hist[t];
    lds[t] = v;
    __syncthreads();
    int inc = v;
    for (int d = 1; d < 256; d <<= 1) {
        int y = (t >= d) ? lds[t - d] : 0;
        __syncthreads();
        inc += y; lds[t] = inc;
        __syncthreads();
    }
    excl[t] = inc - v;
    int node = (bk << 8) + t;
    if (node < n) off[node] = p0 + excl[t];
    __syncthreads();
    for (int i = p0 + t; i < p1; i += 256) {
        uint2 pr = pairs[i];
        int l = (int)(pr.y & 255u);
        int r = atomicAdd(&curl[l], 1);
        csr[p0 + excl[l] + r] = (int)pr.x;
    }
}

// h1 = x @ W1  [N,64] stored bf16; logit halves as1/ad1 [N,2] fp32 * LOG2E.
// LDS-free: W1 column in 64 VGPRs; x broadcast via v_readlane.
__global__ void __launch_bounds__(256, 4)
k_gemm1(const float* __restrict__ x, const float* __restrict__ W1,
        const float* __restrict__ a_src1, const float* __restrict__ a_dst1,
        unsigned short* __restrict__ h1b, float* __restrict__ as1,
        float* __restrict__ ad1, int n) {
    int t = threadIdx.x;
    int lane = t & 63, wid = t >> 6;
    int head = lane >> 5, cc = lane & 31;
    float wreg[64];
#pragma unroll
    for (int k = 0; k < 64; ++k) wreg[k] = W1[k * 64 + lane];
    float asv = a_src1[head * 32 + cc], adv = a_dst1[head * 32 + cc];
    int nwaves = gridDim.x * 4;
    for (int node = blockIdx.x * 4 + wid; node < n; node += nwaves) {
        float xv = x[node * 64 + lane];
        float a0 = 0.f, a1 = 0.f, a2 = 0.f, a3 = 0.f;
#pragma unroll
        for (int k = 0; k < 64; k += 4) {
            a0 = fmaf(rdlane(xv, k + 0), wreg[k + 0], a0);
            a1 = fmaf(rdlane(xv, k + 1), wreg[k + 1], a1);
            a2 = fmaf(rdlane(xv, k + 2), wreg[k + 2], a2);
            a3 = fmaf(rdlane(xv, k + 3), wreg[k + 3], a3);
        }
        float acc = (a0 + a1) + (a2 + a3);
        h1b[node * 64 + lane] = f2bf(acc);
        float ps = acc * asv, pd = acc * adv;
        for (int d = 16; d > 0; d >>= 1) { ps += __shfl_xor(ps, d, 64); pd += __shfl_xor(pd, d, 64); }
        if (cc == 0) { as1[node * 2 + head] = ps * LOG2E; ad1[node * 2 + head] = pd * LOG2E; }
    }
}

// Layer-1 aggregation + bias + exact GELU -> packed bf16 g [N,32 words].
// One wave per node; half-wave per edge row (lane owns 2 channels);
// 8 edges per batch = 4 x (2-edge) steps. (R13 form.)
__global__ void __launch_bounds__(256, 4)
k_agg1(const unsigned int* __restrict__ h1w, const float* __restrict__ as1,
       const float* __restrict__ ad1, const float* __restrict__ b1,
       const int* __restrict__ off, const int* __restrict__ csr_src,
       unsigned int* __restrict__ gw, int n) {
    __shared__ float b1_lds[64];
    int t = threadIdx.x;
    if (t < 64) b1_lds[t] = b1[t];
    __syncthreads();
    int lane = t & 63, wid = t >> 6;
    int h = lane >> 5;          // which edge of the pair
    int c = lane & 31;          // packed word index (channels 2c, 2c+1)
    int head = c >> 4;          // both channels of a word share a head
    int nwaves = gridDim.x * 4;
    for (int node = blockIdx.x * 4 + wid; node < n; node += nwaves) {
        float adh = ad1[node * 2 + head];
        float acc_lo = 0.f, acc_hi = 0.f, wsum = 0.f;
        int p = off[node], pe = off[node + 1];
        for (; p + 8 <= pe; p += 8) {
            int s0 = csr_src[p + 0 + h];
            int s1 = csr_src[p + 2 + h];
            int s2 = csr_src[p + 4 + h];
            int s3 = csr_src[p + 6 + h];
            float a0 = as1[s0 * 2 + head];
            float a1 = as1[s1 * 2 + head];
            float a2 = as1[s2 * 2 + head];
            float a3 = as1[s3 * 2 + head];
            unsigned int u0 = h1w[s0 * 32 + c];
            unsigned int u1 = h1w[s1 * 32 + c];
            unsigned int u2 = h1w[s2 * 32 + c];
            unsigned int u3 = h1w[s3 * 32 + c];
            float w0 = EXP2F(leaky(a0 + adh));
            float w1 = EXP2F(leaky(a1 + adh));
            float w2 = EXP2F(leaky(a2 + adh));
            float w3 = EXP2F(leaky(a3 + adh));
            wsum += (w0 + w1) + (w2 + w3);
            acc_lo = fmaf(w0, bf_lo(u0), acc_lo); acc_hi = fmaf(w0, bf_hi(u0), acc_hi);
            acc_lo = fmaf(w1, bf_lo(u1), acc_lo); acc_hi = fmaf(w1, bf_hi(u1), acc_hi);
            acc_lo = fmaf(w2, bf_lo(u2), acc_lo); acc_hi = fmaf(w2, bf_hi(u2), acc_hi);
            acc_lo = fmaf(w3, bf_lo(u3), acc_lo); acc_hi = fmaf(w3, bf_hi(u3), acc_hi);
        }
        for (; p < pe; p += 2) {
            if (p + h < pe) {
                int s = csr_src[p + h];
                float w = EXP2F(leaky(as1[s * 2 + head] + adh));
                unsigned int u = h1w[s * 32 + c];
                wsum += w;
                acc_lo = fmaf(w, bf_lo(u), acc_lo);
                acc_hi = fmaf(w, bf_hi(u), acc_hi);
            }
        }
        // combine the two half-wave edge streams
        acc_lo += __shfl_xor(acc_lo, 32, 64);
        acc_hi += __shfl_xor(acc_hi, 32, 64);
        wsum   += __shfl_xor(wsum, 32, 64);
        float inv = 1.0f / wsum;
        float g_lo = acc_lo * inv + b1_lds[2 * c];
        float g_hi = acc_hi * inv + b1_lds[2 * c + 1];
        g_lo = 0.5f * g_lo * (1.0f + erff(g_lo * 0.70710678118654752f));
        g_hi = 0.5f * g_hi * (1.0f + erff(g_hi * 0.70710678118654752f));
        if (lane < 32)
            gw[node * 32 + c] = (unsigned int)f2bf(g_lo) | ((unsigned int)f2bf(g_hi) << 16);
    }
}

// h2 = g @ W2 [N,32] packed bf16, plus layer-2 logits as2/ad2 (* LOG2E).
// LDS-free: W2 half-column in 32 VGPRs; g-row via L1-broadcast uint4 loads.
__global__ void __launch_bounds__(256, 4)
k_gemm2(const unsigned int* __restrict__ gw, const float* __restrict__ W2,
        const float* __restrict__ a_src2, const float* __restrict__ a_dst2,
        unsigned int* __restrict__ h2w, float* __restrict__ as2,
        float* __restrict__ ad2, int n) {
    int t = threadIdx.x;
    int lane = t & 63, wid = t >> 6;
    int cc = lane & 31;         // output column
    int kh = lane >> 5;         // K half
    float w2reg[32];
#pragma unroll
    for (int k = 0; k < 32; ++k) w2reg[k] = W2[(kh * 32 + k) * 32 + cc];
    float av_s = a_src2[cc] * LOG2E;
    float av_d = a_dst2[cc] * LOG2E;
    int kh8 = kh * 8;
    int nwaves = gridDim.x * 4;
    for (int node = blockIdx.x * 4 + wid; node < n; node += nwaves) {
        const uint4* gp = reinterpret_cast<const uint4*>(&gw[node * 32 + kh8 * 2]);
        uint4 ga = gp[0];
        uint4 gb = gp[1];
        float acc2 = 0.f;
        acc2 = fmaf(bf_lo(ga.x), w2reg[0], acc2);  acc2 = fmaf(bf_hi(ga.x), w2reg[1], acc2);
        acc2 = fmaf(bf_lo(ga.y), w2reg[2], acc2);  acc2 = fmaf(bf_hi(ga.y), w2reg[3], acc2);
        acc2 = fmaf(bf_lo(ga.z), w2reg[4], acc2);  acc2 = fmaf(bf_hi(ga.z), w2reg[5], acc2);
        acc2 = fmaf(bf_lo(ga.w), w2reg[6], acc2);  acc2 = fmaf(bf_hi(ga.w), w2reg[7], acc2);
        acc2 = fmaf(bf_lo(gb.x), w2reg[8], acc2);  acc2 = fmaf(bf_hi(gb.x), w2reg[9], acc2);
        acc2 = fmaf(bf_lo(gb.y), w2reg[10], acc2); acc2 = fmaf(bf_hi(gb.y), w2reg[11], acc2);
        acc2 = fmaf(bf_lo(gb.z), w2reg[12], acc2); acc2 = fmaf(bf_hi(gb.z), w2reg[13], acc2);
        acc2 = fmaf(bf_lo(gb.w), w2reg[14], acc2); acc2 = fmaf(bf_hi(gb.w), w2reg[15], acc2);
        uint4 gc = gp[2];
        uint4 gd = gp[3];
        acc2 = fmaf(bf_lo(gc.x), w2reg[16], acc2); acc2 = fmaf(bf_hi(gc.x), w2reg[17], acc2);
        acc2 = fmaf(bf_lo(gc.y), w2reg[18], acc2); acc2 = fmaf(bf_hi(gc.y), w2reg[19], acc2);
        acc2 = fmaf(bf_lo(gc.z), w2reg[20], acc2); acc2 = fmaf(bf_hi(gc.z), w2reg[21], acc2);
        acc2 = fmaf(bf_lo(gc.w), w2reg[22], acc2); acc2 = fmaf(bf_hi(gc.w), w2reg[23], acc2);
        acc2 = fmaf(bf_lo(gd.x), w2reg[24], acc2); acc2 = fmaf(bf_hi(gd.x), w2reg[25], acc2);
        acc2 = fmaf(bf_lo(gd.y), w2reg[26], acc2); acc2 = fmaf(bf_hi(gd.y), w2reg[27], acc2);
        acc2 = fmaf(bf_lo(gd.z), w2reg[28], acc2); acc2 = fmaf(bf_hi(gd.z), w2reg[29], acc2);
        acc2 = fmaf(bf_lo(gd.w), w2reg[30], acc2); acc2 = fmaf(bf_hi(gd.w), w2reg[31], acc2);
        acc2 += __shfl_xor(acc2, 32, 64);       // full K sum, all lanes
        float ps = acc2 * av_s;
        float pd = acc2 * av_d;
        for (int d = 16; d > 0; d >>= 1) { ps += __shfl_xor(ps, d, 32); pd += __shfl_xor(pd, d, 32); }
        float nb = __shfl_xor(acc2, 1, 32);     // neighbor column value
        if (lane < 32 && !(cc & 1))
            h2w[node * 16 + (cc >> 1)] = (unsigned int)f2bf(acc2) | ((unsigned int)f2bf(nb) << 16);
        if (lane == 0) { as2[node] = ps; ad2[node] = pd; }
    }
}

// Layer-2 aggregation: one wave per node, quarter-wave per edge row
// (lane owns 2 of 32 channels); 16-edge and 8-edge batch tiers. (R13 form.)
__global__ void __launch_bounds__(256, 4)
k_agg2(const unsigned int* __restrict__ h2w, const float* __restrict__ as2,
       const float* __restrict__ ad2, const float* __restrict__ b2,
       const int* __restrict__ off, const int* __restrict__ csr_src,
       float* __restrict__ out, int n) {
    int t = threadIdx.x;
    int lane = t & 63, wid = t >> 6;
    int q = lane >> 4;          // which edge of the quad
    int c = lane & 15;          // packed word index (channels 2c, 2c+1)
    int nwaves = gridDim.x * 4;
    for (int node = blockIdx.x * 4 + wid; node < n; node += nwaves) {
        float adv = ad2[node];
        float acc_lo = 0.f, acc_hi = 0.f, wsum = 0.f;
        int p = off[node], pe = off[node + 1];
        for (; p + 16 <= pe; p += 16) {
            int s0 = csr_src[p + 0 + q];
            int s1 = csr_src[p + 4 + q];
            int s2 = csr_src[p + 8 + q];
            int s3 = csr_src[p + 12 + q];
            float a0 = as2[s0], a1 = as2[s1], a2 = as2[s2], a3 = as2[s3];
            unsigned int u0 = h2w[s0 * 16 + c];
            unsigned int u1 = h2w[s1 * 16 + c];
            unsigned int u2 = h2w[s2 * 16 + c];
            unsigned int u3 = h2w[s3 * 16 + c];
            float w0 = EXP2F(leaky(a0 + adv));
            float w1 = EXP2F(leaky(a1 + adv));
            float w2 = EXP2F(leaky(a2 + adv));
            float w3 = EXP2F(leaky(a3 + adv));
            wsum += (w0 + w1) + (w2 + w3);
            acc_lo = fmaf(w0, bf_lo(u0), acc_lo); acc_hi = fmaf(w0, bf_hi(u0), acc_hi);
            acc_lo = fmaf(w1, bf_lo(u1), acc_lo); acc_hi = fmaf(w1, bf_hi(u1), acc_hi);
            acc_lo = fmaf(w2, bf_lo(u2), acc_lo); acc_hi = fmaf(w2, bf_hi(u2), acc_hi);
            acc_lo = fmaf(w3, bf_lo(u3), acc_lo); acc_hi = fmaf(w3, bf_hi(u3), acc_hi);
        }
        for (; p + 8 <= pe; p += 8) {
            int s0 = csr_src[p + 0 + q];
            int s1 = csr_src[p + 4 + q];
            float a0 = as2[s0], a1 = as2[s1];
            unsigned int u0 = h2w[s0 * 16 + c];
            unsigned int u1 = h2w[s1 * 16 + c];
            float w0 = EXP2F(leaky(a0 + adv));
            float w1 = EXP2F(leaky(a1 + adv));
            wsum += w0 + w1;
            acc_lo = fmaf(w0, bf_lo(u0), acc_lo); acc_hi = fmaf(w0, bf_hi(u0), acc_hi);
            acc_lo = fmaf(w1, bf_lo(u1), acc_lo); acc_hi = fmaf(w1, bf_hi(u1), acc_hi);
        }
        for (; p < pe; p += 4) {
            if (p + q < pe) {
                int s = csr_src[p + q];
                float w = EXP2F(leaky(as2[s] + adv));
                unsigned int u = h2w[s * 16 + c];
                wsum += w;
                acc_lo = fmaf(w, bf_lo(u), acc_lo);
                acc_hi = fmaf(w, bf_hi(u), acc_hi);
            }
        }
        // combine the four quarter-wave edge streams
        acc_lo += __shfl_xor(acc_lo, 32, 64);
        acc_hi += __shfl_xor(acc_hi, 32, 64);
        wsum   += __shfl_xor(wsum, 32, 64);
        acc_lo += __shfl_xor(acc_lo, 16, 64);
        acc_hi += __shfl_xor(acc_hi, 16, 64);
        wsum   += __shfl_xor(wsum, 16, 64);
        if (lane < 16) {
            float inv = 1.0f / wsum;
            float2 o;
            o.x = acc_lo * inv + b2[2 * c];
            o.y = acc_hi * inv + b2[2 * c + 1];
            *reinterpret_cast<float2*>(&out[node * 32 + 2 * c]) = o;
        }
    }
}

extern "C" void kernel_launch(void* const* d_in, const int* in_sizes, int n_in,
                              void* d_out, int out_size, void* d_ws, size_t ws_size,
                              hipStream_t stream) {
    const float* x      = (const float*)d_in[0];
    const int*   ei     = (const int*)d_in[1];
    const float* W1     = (const float*)d_in[2];
    const float* a_src1 = (const float*)d_in[3];
    const float* a_dst1 = (const float*)d_in[4];
    const float* b1     = (const float*)d_in[5];
    const float* W2     = (const float*)d_in[6];
    const float* a_src2 = (const float*)d_in[7];
    const float* a_dst2 = (const float*)d_in[8];
    const float* b2     = (const float*)d_in[9];
    float* out = (float*)d_out;

    int n   = in_sizes[0] / 64;
    int E   = in_sizes[1] / 2;
    int tot = E + n;
    const int MATN = NBK * NB;   // 131072

    char* w = (char*)d_ws;
    int* off   = (int*)w; w += sizeof(int) * (size_t)(n + 1);
    int* bsum  = (int*)w; w += sizeof(int) * 1024;
    int* csr   = (int*)w; w += sizeof(int) * (size_t)tot;
    int* mat   = (int*)w; w += sizeof(int) * (size_t)MATN;
    int* mat_s = (int*)w; w += sizeof(int) * (size_t)(MATN + 1);
    int* bbase = (int*)w; w += sizeof(int) * (NBK + 1);
    unsigned short* h1b = (unsigned short*)w; w += sizeof(unsigned short) * (size_t)n * 64;
    float* as1 = (float*)w; w += sizeof(float) * (size_t)n * 2;
    float* ad1 = (float*)w; w += sizeof(float) * (size_t)n * 2;
    unsigned int* gw = (unsigned int*)w; w += sizeof(unsigned int) * (size_t)n * 32;
    float* as2v = (float*)w; w += sizeof(float) * (size_t)n;
    float* ad2v = (float*)w; w += sizeof(float) * (size_t)n;
    // pairs ([tot] uint2, 13.6MB) aliases h1b..as1 (written only after k_bsort).
    uint2* pairs = (uint2*)(((uintptr_t)h1b + 15) & ~(uintptr_t)15);
    // h2 (packed bf16, [n,16 words]) aliases h1b (dead after k_agg1).
    unsigned int* h2w = (unsigned int*)h1b;

    k_binhist2<<<NB, 256, 0, stream>>>(ei, E, n, mat);
    k_scan1<<<MATN / 2048, 256, 0, stream>>>(mat, mat_s, bsum, MATN);
    k_scan3<<<(MATN + 255) / 256, 256, 0, stream>>>(mat_s, bsum, MATN, tot, bbase, off, n);
    k_part2<<<NB, 256, 0, stream>>>(ei, E, n, mat_s, pairs);
    k_bsort<<<NBK, 256, 0, stream>>>(pairs, bbase, n, off, csr);
    k_gemm1<<<1024, 256, 0, stream>>>(x, W1, a_src1, a_dst1, h1b, as1, ad1, n);
    k_agg1<<<2048, 256, 0, stream>>>((const unsigned int*)h1b, as1, ad1, b1,
                                     off, csr, gw, n);
    k_gemm2<<<1024, 256, 0, stream>>>(gw, W2, a_src2, a_dst2, h2w, as2v, ad2v, n);
    k_agg2<<<2048, 256, 0, stream>>>(h2w, as2v, ad2v, b2, off, csr, out, n);
}